// Round 18
// baseline (253.077 us; speedup 1.0000x reference)
//
#include <hip/hip_runtime.h>
#include <hip/hip_bf16.h>

typedef __attribute__((ext_vector_type(4))) int i32x4;
typedef __attribute__((ext_vector_type(16))) int i32x16;

#define M_DIM 8192
#define N_DIM 8192
#define K_DIM 2048
#define WCOUNT (N_DIM * K_DIM)

// Fragment-major layout: frag[t32][kc][l] : byte = t32*65536 + kc*512 + l*16.
// One 32x32x32 MFMA operand fragment = contiguous 1024-B wave access at
// base + lane*16 (lane = kg*32+l31 reads row l31, chunk 2ks+kg). Verified
// end-to-end in R11 (B operand ran register-direct from this layout, absmax 2.0).

// ---------------- kernel 1: per-block partial sums of |w| ----------------
__global__ __launch_bounds__(256) void k_abs_partial(const float* __restrict__ w,
                                                     float* __restrict__ part) {
    int tid = blockIdx.x * 256 + threadIdx.x;
    const float4* w4 = (const float4*)w;
    float s = 0.0f;
    const int total4 = WCOUNT / 4;
    for (int i = tid; i < total4; i += 2048 * 256) {
        float4 v = w4[i];
        s += fabsf(v.x) + fabsf(v.y) + fabsf(v.z) + fabsf(v.w);
    }
    #pragma unroll
    for (int off = 1; off < 64; off <<= 1) s += __shfl_xor(s, off);
    __shared__ float red[4];
    if ((threadIdx.x & 63) == 0) red[threadIdx.x >> 6] = s;
    __syncthreads();
    if (threadIdx.x == 0)
        part[blockIdx.x] = (red[0] + red[1]) + (red[2] + red[3]);
}

// ---------------- kernel 2: deterministic final reduce -> sum|w| ----------------
__global__ __launch_bounds__(256) void k_abs_final(const float* __restrict__ part,
                                                   float* __restrict__ sum) {
    int t = threadIdx.x;
    float s = 0.0f;
    #pragma unroll
    for (int i = 0; i < 8; i++) s += part[t + i * 256];
    #pragma unroll
    for (int off = 1; off < 64; off <<= 1) s += __shfl_xor(s, off);
    __shared__ float red[4];
    if ((t & 63) == 0) red[t >> 6] = s;
    __syncthreads();
    if (t == 0) sum[0] = (red[0] + red[1]) + (red[2] + red[3]);
}

// -------- kernel 3: ternary weight quant -> int8, fragment-major --------
__global__ __launch_bounds__(256) void k_wquant(const float* __restrict__ w,
                                                const float* __restrict__ sum,
                                                signed char* __restrict__ wqf) {
    const float thr = 0.5f * (sum[0] * (1.0f / 16777216.0f));
    const int g = blockIdx.x * 256 + threadIdx.x;
    const int n = g >> 7;
    const int kc = g & 127;
    const float4* wr = (const float4*)(w + (size_t)n * K_DIM + kc * 16);
    union { signed char c[16]; uint4 v; } pk;
    #pragma unroll
    for (int q = 0; q < 4; q++) {
        float4 v = wr[q];
        pk.c[q * 4 + 0] = v.x > thr ? 1 : (v.x < -thr ? -1 : 0);
        pk.c[q * 4 + 1] = v.y > thr ? 1 : (v.y < -thr ? -1 : 0);
        pk.c[q * 4 + 2] = v.z > thr ? 1 : (v.z < -thr ? -1 : 0);
        pk.c[q * 4 + 3] = v.w > thr ? 1 : (v.w < -thr ? -1 : 0);
    }
    *(uint4*)(wqf + (size_t)(n >> 5) * 65536 + kc * 512 + (n & 31) * 16) = pk.v;
}

// -------- kernel 4: activation quant -> int8 fragment-major + coef --------
__global__ __launch_bounds__(256) void k_xquant(const float* __restrict__ x,
                                                const float* __restrict__ sum,
                                                signed char* __restrict__ xqf,
                                                float* __restrict__ coef) {
    const int row = blockIdx.x;
    const int t = threadIdx.x;
    const float4* xr = (const float4*)(x + (size_t)row * K_DIM);
    float4 a = xr[t * 2];
    float4 b = xr[t * 2 + 1];
    float m = fmaxf(fmaxf(fmaxf(fabsf(a.x), fabsf(a.y)), fmaxf(fabsf(a.z), fabsf(a.w))),
                    fmaxf(fmaxf(fabsf(b.x), fabsf(b.y)), fmaxf(fabsf(b.z), fabsf(b.w))));
    #pragma unroll
    for (int off = 1; off < 64; off <<= 1) m = fmaxf(m, __shfl_xor(m, off));
    __shared__ float red[4];
    if ((t & 63) == 0) red[t >> 6] = m;
    __syncthreads();
    m = fmaxf(fmaxf(red[0], red[1]), fmaxf(red[2], red[3]));
    const float sc = fmaxf(m, 1e-5f);
    if (t == 0) coef[row] = (sum[0] * (1.0f / 16777216.0f)) / sc;
    const float r = 127.0f / sc;
    float q[8] = {a.x, a.y, a.z, a.w, b.x, b.y, b.z, b.w};
    union { signed char c[8]; uint2 v; } pk;
    #pragma unroll
    for (int j = 0; j < 8; j++) {
        float v = rintf(q[j] * r);
        v = fminf(fmaxf(v, -127.0f), 127.0f);
        pk.c[j] = (signed char)v;
    }
    *(uint2*)(xqf + (size_t)(row >> 5) * 65536 + (t >> 1) * 512
              + (row & 31) * 16 + (t & 1) * 8) = pk.v;
}

// ---------------- kernel 5: 128x128 i8 GEMM — NO LDS, NO BARRIERS ----------------
// Every barrier-structured variant (R3-R17, 10 configs) sits at a serial-port
// fixed point: barriers keep waves in phase, so the LDS port and the MFMA pipe
// alternate instead of overlapping (step = LDS-time + MFMA-time, fits R11/R12
// exactly). This kernel removes the mechanism: both operands are loaded
// REGISTER-DIRECT from L2 via fragment-major 1024-B contiguous wave loads
// (layout verified in R11's B path), 1-K-tile register double-buffer (fx/fy,
// fully-unrolled static indexing), ZERO barriers / ZERO manual waitcnts —
// compiler-tracked deps only. Waves free-run and drift; L2 service overlaps
// MFMA across waves. L2 demand ~55 B/cyc/CU vs ~135 available -> MFMA-bound.
// 256 thr / 4 waves (2Mx2N of 64x64); acc 64 AGPR + ~90 VGPR -> 3 blocks/CU.
__global__ __launch_bounds__(256, 3) void k_gemm(const signed char* __restrict__ xqf,
                                                 const signed char* __restrict__ wqf,
                                                 const float* __restrict__ coef,
                                                 float* __restrict__ out) {
    const int t = threadIdx.x;
    const int lane = t & 63;
    const int wid = t >> 6;
    const int wm = wid >> 1;
    const int wn = wid & 1;
    const int l31 = lane & 31;
    const int kg = lane >> 5;

    // L2 map (R12): XCD x owns brows [8x,8x+8); per XCD, groups of 4 bcols sweep.
    const int bid = blockIdx.x;
    const int xcd = bid & 7;
    const int idx = bid >> 3;
    const int grp = idx >> 5;
    const int w_ = idx & 31;
    const int bcol = grp * 4 + (w_ & 3);
    const int brow = xcd * 8 + ((w_ >> 2) & 7);

    // fragment base pointers (advance 4096 B per 2 K-tiles)
    const signed char* pa0 = xqf + (size_t)(brow * 4 + wm * 2) * 65536 + lane * 16;
    const signed char* pa1 = pa0 + 65536;
    const signed char* pb0 = wqf + (size_t)(bcol * 4 + wn * 2) * 65536 + lane * 16;
    const signed char* pb1 = pb0 + 65536;

    i32x16 c00 = (i32x16){0,0,0,0,0,0,0,0,0,0,0,0,0,0,0,0};
    i32x16 c01 = c00, c10 = c00, c11 = c00;
    i32x4 fx[8], fy[8];   // [mt*2+ks] A, [4+nt*2+ks] B — all indices static

#define LOADF(F, o) do {                                                           \
        F[0] = *(const i32x4*)(pa0 + (o));                                         \
        F[1] = *(const i32x4*)(pa0 + (o) + 1024);                                  \
        F[2] = *(const i32x4*)(pa1 + (o));                                         \
        F[3] = *(const i32x4*)(pa1 + (o) + 1024);                                  \
        F[4] = *(const i32x4*)(pb0 + (o));                                         \
        F[5] = *(const i32x4*)(pb0 + (o) + 1024);                                  \
        F[6] = *(const i32x4*)(pb1 + (o));                                         \
        F[7] = *(const i32x4*)(pb1 + (o) + 1024); } while (0)
#define MMF(F) do {                                                                \
        __builtin_amdgcn_s_setprio(1);                                             \
        c00 = __builtin_amdgcn_mfma_i32_32x32x32_i8(F[0], F[4], c00, 0, 0, 0);     \
        c01 = __builtin_amdgcn_mfma_i32_32x32x32_i8(F[0], F[6], c01, 0, 0, 0);     \
        c10 = __builtin_amdgcn_mfma_i32_32x32x32_i8(F[2], F[4], c10, 0, 0, 0);     \
        c11 = __builtin_amdgcn_mfma_i32_32x32x32_i8(F[2], F[6], c11, 0, 0, 0);     \
        c00 = __builtin_amdgcn_mfma_i32_32x32x32_i8(F[1], F[5], c00, 0, 0, 0);     \
        c01 = __builtin_amdgcn_mfma_i32_32x32x32_i8(F[1], F[7], c01, 0, 0, 0);     \
        c10 = __builtin_amdgcn_mfma_i32_32x32x32_i8(F[3], F[5], c10, 0, 0, 0);     \
        c11 = __builtin_amdgcn_mfma_i32_32x32x32_i8(F[3], F[7], c11, 0, 0, 0);     \
        __builtin_amdgcn_s_setprio(0); } while (0)

    LOADF(fx, 0);                       // kt0
    #pragma unroll 1
    for (int j = 0; j < 15; j++) {
        LOADF(fy, 2048);                // kt 2j+1
        MMF(fx);                        // kt 2j
        pa0 += 4096; pa1 += 4096; pb0 += 4096; pb1 += 4096;
        LOADF(fx, 0);                   // kt 2j+2
        MMF(fy);                        // kt 2j+1
    }
    LOADF(fy, 2048);                    // kt31
    MMF(fx);                            // kt30
    MMF(fy);                            // kt31

    // ---- epilogue: out = (max(acc * coef[row], 0))^2, direct NT stores.
    // 32x32 C/D: col = lane&31, row = (r&3) + 8*(r>>2) + 4*(lane>>5)
    const int rb = brow * 128 + wm * 64 + 4 * kg;
    const int cb = bcol * 128 + wn * 64 + l31;
    #pragma unroll
    for (int mt = 0; mt < 2; mt++) {
        const i32x16 ac0 = mt ? c10 : c00;
        const i32x16 ac1 = mt ? c11 : c01;
        #pragma unroll
        for (int r = 0; r < 16; r++) {
            const int grow = rb + mt * 32 + (r & 3) + 8 * (r >> 2);
            const float c = coef[grow];
            float v0 = (float)ac0[r] * c; v0 = fmaxf(v0, 0.0f);
            float v1 = (float)ac1[r] * c; v1 = fmaxf(v1, 0.0f);
            __builtin_nontemporal_store(v0 * v0, &out[(size_t)grow * N_DIM + cb]);
            __builtin_nontemporal_store(v1 * v1, &out[(size_t)grow * N_DIM + cb + 32]);
        }
    }
#undef LOADF
#undef MMF
}

// ---------------- launch ----------------
extern "C" void kernel_launch(void* const* d_in, const int* in_sizes, int n_in,
                              void* d_out, int out_size, void* d_ws, size_t ws_size,
                              hipStream_t stream) {
    const float* x = (const float*)d_in[0];   // [4,2048,2048] fp32
    const float* w = (const float*)d_in[1];   // [8192,2048] fp32
    float* out = (float*)d_out;               // [4,2048,8192] fp32

    char* ws = (char*)d_ws;
    float* sum   = (float*)ws;
    float* part  = (float*)(ws + 256);
    float* coef  = (float*)(ws + 49152);
    signed char* xqf = (signed char*)(ws + 131072);
    signed char* wqf = (signed char*)(ws + 131072 + 16777216);

    k_abs_partial<<<2048, 256, 0, stream>>>(w, part);
    k_abs_final<<<1, 256, 0, stream>>>(part, sum);
    k_wquant<<<4096, 256, 0, stream>>>(w, sum, wqf);
    k_xquant<<<M_DIM, 256, 0, stream>>>(x, sum, xqf, coef);
    k_gemm<<<dim3(4096), 256, 0, stream>>>(xqf, wqf, coef, out);
}